// Round 11
// baseline (184.527 us; speedup 1.0000x reference)
//
#include <hip/hip_runtime.h>
#include <cstdint>

#define EMBED 1024
#define HEADS 16
#define HDIM  64
#define SEQ   2048
#define BATCH 2
#define ROWS  (BATCH*SEQ)   // 4096

typedef __bf16 bf16x8 __attribute__((ext_vector_type(8)));
typedef float  f32x4  __attribute__((ext_vector_type(4)));
typedef float  f32x16 __attribute__((ext_vector_type(16)));
typedef unsigned int uint32x2 __attribute__((ext_vector_type(2)));

__device__ __forceinline__ unsigned short f2bf(float f) {
    union { float f; uint32_t u; } v; v.f = f;
    uint32_t r = v.u + 0x7fffu + ((v.u >> 16) & 1u);
    return (unsigned short)(r >> 16);
}

__device__ __forceinline__ uint32_t cvtpk_bf16(float lo, float hi) {
    uint32_t r;
    asm("v_cvt_pk_bf16_f32 %0, %1, %2" : "=v"(r) : "v"(lo), "v"(hi));
    return r;
}

// hardware 2^x (quarter-rate, 1 inst; exp2f without -ffast-math is a libm call)
__device__ __forceinline__ float fexp2(float x) {
    float r;
    asm("v_exp_f32 %0, %1" : "=v"(r) : "v"(x));
    return r;
}

#define GLDS(src, dst) __builtin_amdgcn_global_load_lds( \
    (const __attribute__((address_space(1))) uint32_t*)(src), \
    (__attribute__((address_space(3))) uint32_t*)(dst), 16, 0, 0)

// ---------------- fused prep: ALL FOUR weight transposes + LN1, one launch ----------------
__global__ __launch_bounds__(256) void k_prep(
    const float* __restrict__ w_qkv, const float* __restrict__ w_proj,
    const float* __restrict__ w1,    const float* __restrict__ w2,
    unsigned short* __restrict__ wqkvT, unsigned short* __restrict__ wprojT,
    unsigned short* __restrict__ w1T,   unsigned short* __restrict__ w2T,
    const float* __restrict__ x, const float* __restrict__ g1,
    const float* __restrict__ be1, unsigned short* __restrict__ h)
{
    int b = blockIdx.x;
    if (b >= 12288) {
        // ---- LN1 ----
        const int row = b - 12288, t = threadIdx.x;
        float4 v = ((const float4*)(x + (size_t)row * EMBED))[t];
        float s = v.x + v.y + v.z + v.w;
        float q = v.x*v.x + v.y*v.y + v.z*v.z + v.w*v.w;
#pragma unroll
        for (int off = 32; off >= 1; off >>= 1) {
            s += __shfl_xor(s, off, 64);
            q += __shfl_xor(q, off, 64);
        }
        __shared__ float ss[4], sq[4];
        if ((t & 63) == 0) { ss[t >> 6] = s; sq[t >> 6] = q; }
        __syncthreads();
        s = ss[0] + ss[1] + ss[2] + ss[3];
        q = sq[0] + sq[1] + sq[2] + sq[3];
        const float mu  = s * (1.0f / EMBED);
        const float var = q * (1.0f / EMBED) - mu * mu;
        const float rs  = rsqrtf(var + 1e-5f);
        float4 gv = ((const float4*)g1)[t];
        float4 bv = ((const float4*)be1)[t];
        ushort4 o;
        o.x = f2bf((v.x - mu) * rs * gv.x + bv.x);
        o.y = f2bf((v.y - mu) * rs * gv.y + bv.y);
        o.z = f2bf((v.z - mu) * rs * gv.z + bv.z);
        o.w = f2bf((v.w - mu) * rs * gv.w + bv.w);
        ((ushort4*)(h + (size_t)row * EMBED))[t] = o;
        return;
    }
    const float* in; unsigned short* out; int N, K, nx;
    if (b < 3072)      {           in = w_qkv;  out = wqkvT;  K = 1024; N = 3072; nx = 96; }
    else if (b < 4096) { b -= 3072; in = w_proj; out = wprojT; K = 1024; N = 1024; nx = 32; }
    else if (b < 8192) { b -= 4096; in = w1;     out = w1T;    K = 1024; N = 4096; nx = 128; }
    else               { b -= 8192; in = w2;     out = w2T;    K = 4096; N = 1024; nx = 32; }
    const int n0 = (b % nx) * 32, k0 = (b / nx) * 32;

    __shared__ float tile[32][33];
    const int tx = threadIdx.x & 31, ty = threadIdx.x >> 5;
#pragma unroll
    for (int r = 0; r < 4; ++r)
        tile[ty + 8*r][tx] = in[(size_t)(k0 + ty + 8*r) * N + n0 + tx];
    __syncthreads();
#pragma unroll
    for (int r = 0; r < 4; ++r)
        out[(size_t)(n0 + ty + 8*r) * K + k0 + tx] = f2bf(tile[tx][ty + 8*r]);
}

// ---------------- LayerNorm: fp32 in -> bf16 out (LN2) ----------------
__global__ __launch_bounds__(256) void k_layernorm(
    const float* __restrict__ x, const float* __restrict__ g, const float* __restrict__ b,
    unsigned short* __restrict__ h)
{
    const int row = blockIdx.x, t = threadIdx.x;
    float4 v = ((const float4*)(x + (size_t)row * EMBED))[t];
    float s = v.x + v.y + v.z + v.w;
    float q = v.x*v.x + v.y*v.y + v.z*v.z + v.w*v.w;
#pragma unroll
    for (int off = 32; off >= 1; off >>= 1) {
        s += __shfl_xor(s, off, 64);
        q += __shfl_xor(q, off, 64);
    }
    __shared__ float ss[4], sq[4];
    if ((t & 63) == 0) { ss[t >> 6] = s; sq[t >> 6] = q; }
    __syncthreads();
    s = ss[0] + ss[1] + ss[2] + ss[3];
    q = sq[0] + sq[1] + sq[2] + sq[3];
    const float mu  = s * (1.0f / EMBED);
    const float var = q * (1.0f / EMBED) - mu * mu;
    const float rs  = rsqrtf(var + 1e-5f);
    float4 gv = ((const float4*)g)[t];
    float4 bv = ((const float4*)b)[t];
    ushort4 o;
    o.x = f2bf((v.x - mu) * rs * gv.x + bv.x);
    o.y = f2bf((v.y - mu) * rs * gv.y + bv.y);
    o.z = f2bf((v.z - mu) * rs * gv.z + bv.z);
    o.w = f2bf((v.w - mu) * rs * gv.w + bv.w);
    ((ushort4*)(h + (size_t)row * EMBED))[t] = o;
}

// ---------------- bf16 TN GEMM v10: 128x128, quadrant waves, 4-BUF SINGLE-BARRIER loop -----
// R8-verified: -3.7us on FF2 vs 2-barrier. FLAGS: 1=bias, 2=relu, 4=residual(fp32).
template<int FLAGS, typename OutT>
__global__ __launch_bounds__(512) void k_gemm_bt(
    const unsigned short* __restrict__ A,
    const unsigned short* __restrict__ BT,
    const float* __restrict__ bias,
    const float* __restrict__ resid,
    OutT* __restrict__ C,
    int M, int N, int K)
{
    __shared__ uint4 ldsv[8192];       // 128 KiB: 4 bufs x [A 16K | B 16K]
    char* base = (char*)ldsv;
    char* aL = base;
    char* bL = base + 16384;
    const int t = threadIdx.x, l = t & 63, w = t >> 6;
    const int pos = w & 3, kh = w >> 2;
    const int qr = pos >> 1, qc = pos & 1;
    const int g = l >> 4, c = l & 15;

    const int gx = gridDim.x;
    const int lin = blockIdx.y * gx + blockIdx.x;
    const int cpx = (gx * gridDim.y) >> 3;
    const int swz = (lin & 7) * cpx + (lin >> 3);
    const int row0 = (swz / gx) * 128, col0 = (swz % gx) * 128;

    const int swc = (((l & 7) ^ (l >> 3)) * 8);
    const int rA0 = w*16 + (l >> 3), rA1 = rA0 + 8;
    const unsigned short* aS0 = A  + (size_t)(row0 + rA0) * K + swc;
    const unsigned short* aS1 = A  + (size_t)(row0 + rA1) * K + swc;
    const unsigned short* bS0 = BT + (size_t)(col0 + rA0) * K + swc;
    const unsigned short* bS1 = BT + (size_t)(col0 + rA1) * K + swc;
    const int dst0 = w * 2048, dst1 = w * 2048 + 1024;

    f32x4 acc[4][4];
#pragma unroll
    for (int m = 0; m < 4; ++m)
#pragma unroll
        for (int n = 0; n < 4; ++n) acc[m][n] = f32x4{0.f, 0.f, 0.f, 0.f};

    auto stage = [&](int kt, int bo) {
        const size_t ko = (size_t)kt * 64;
        GLDS(aS0 + ko, aL + bo + dst0);
        GLDS(aS1 + ko, aL + bo + dst1);
        GLDS(bS0 + ko, bL + bo + dst0);
        GLDS(bS1 + ko, bL + bo + dst1);
    };
    auto compute = [&](int bo) {
        const int chb = ((kh*4 + g) ^ (c & 7)) * 16;
        bf16x8 af[4], bfr[4];
#pragma unroll
        for (int m = 0; m < 4; ++m)
            af[m] = *(const bf16x8*)(aL + bo + (qr*64 + m*16 + c) * 128 + chb);
#pragma unroll
        for (int n = 0; n < 4; ++n)
            bfr[n] = *(const bf16x8*)(bL + bo + (qc*64 + n*16 + c) * 128 + chb);
        __builtin_amdgcn_s_setprio(1);
#pragma unroll
        for (int m = 0; m < 4; ++m)
#pragma unroll
            for (int n = 0; n < 4; ++n)
                acc[m][n] = __builtin_amdgcn_mfma_f32_16x16x32_bf16(af[m], bfr[n], acc[m][n], 0, 0, 0);
        __builtin_amdgcn_s_setprio(0);
    };

    const int nkt = K >> 6;
    stage(0, 0);
    stage(1, 32768);
    for (int kt = 0; kt < nkt; ++kt) {
        const int bo = (kt & 3) * 32768;
        if (kt + 2 < nkt) {
            stage(kt + 2, ((kt + 2) & 3) * 32768);
            asm volatile("s_waitcnt vmcnt(8)" ::: "memory");
        } else if (kt + 1 < nkt) {
            asm volatile("s_waitcnt vmcnt(4)" ::: "memory");
        } else {
            asm volatile("s_waitcnt vmcnt(0)" ::: "memory");
        }
        __builtin_amdgcn_s_barrier();
        compute(bo);
    }

    asm volatile("s_waitcnt lgkmcnt(0)" ::: "memory");
    __builtin_amdgcn_s_barrier();
    if (kh) {
#pragma unroll
        for (int m = 0; m < 4; ++m)
#pragma unroll
            for (int n = 0; n < 4; ++n)
                *(f32x4*)(base + (((pos*16 + m*4 + n) * 64) + l) * 16) = acc[m][n];
    }
    asm volatile("s_waitcnt lgkmcnt(0)" ::: "memory");
    __builtin_amdgcn_s_barrier();

    if (!kh) {
#pragma unroll
        for (int m = 0; m < 4; ++m) {
            const int rb = row0 + qr*64 + m*16 + g*4;
#pragma unroll
            for (int n = 0; n < 4; ++n) {
                const f32x4 part = *(const f32x4*)(base + (((pos*16 + m*4 + n) * 64) + l) * 16);
                const int col = col0 + qc*64 + n*16 + c;
                float bv = 0.f;
                if constexpr ((FLAGS & 1) != 0) bv = bias[col];
#pragma unroll
                for (int j = 0; j < 4; ++j) {
                    float v = acc[m][n][j] + part[j] + bv;
                    if constexpr ((FLAGS & 2) != 0) v = fmaxf(v, 0.f);
                    if constexpr ((FLAGS & 4) != 0) v += resid[(size_t)(rb + j) * N + col];
                    if constexpr (sizeof(OutT) == 2) C[(size_t)(rb + j) * N + col] = (OutT)f2bf(v);
                    else                             C[(size_t)(rb + j) * N + col] = v;
                }
            }
        }
    }
}

// ---------------- bf16 TN GEMM vFF1: 256x128 tile, quadrant(128x64)x2-K-half waves ---------
// R10 analysis: 256^2-class runs 11.7 B/cy/CU staged vs 128^2-quadrant class 20.7; the gap
// tracks LDS-read bytes per staged byte (3.0 vs 2.0 -- 2x4 wave split re-reads A x4, B x2).
// This tile keeps ratio 2.0 (per wave (128+64)x32x2 = 12KB/tile) at 1.5x bigger tile than
// 128^2 -> staged volume 384MB (vs 512 at 128^2, 256 at 256^2) at the fast-class rate.
// acc[8][4] = 128 VGPR (the 256^2-quadrant variant needs 256 -> cliff; this fits at 2 w/SIMD).
// 3 bufs x 48KB = 144KB; single barrier is safe ONLY because stage(kt+2) is issued AFTER
// barrier(kt): all waves passed barrier(kt) => completed compute(kt-1) => done reading
// buf[(kt+2)%3] = buf[(kt-1)%3]. (Issuing stage before the barrier would race at 3 bufs.)
// vmcnt(6): 6 GLDS/wave/stage; outstanding before barrier <= 12 -> waits stage(kt) only,
// stage(kt+1) keeps ~1.2 iters of flight (T4: never 0 mid-loop).
// K-halves combined at the end via 128KB LDS exchange (v9/v10 pattern).
__global__ __launch_bounds__(512) __attribute__((amdgpu_waves_per_eu(2, 2)))
void k_gemm_ff1(
    const unsigned short* __restrict__ A,
    const unsigned short* __restrict__ BT,
    const float* __restrict__ bias,
    unsigned short* __restrict__ C,
    int N, int K)                       // N=4096 out cols, K=1024
{
    __shared__ uint4 ldsv[9216];        // 144 KiB: 3 bufs x [A 32K | B 16K]
    char* base = (char*)ldsv;
    const int t = threadIdx.x, l = t & 63, w = t >> 6;
    const int pos = w & 3, kh = w >> 2;           // quadrant pos, K-half kh
    const int qr = pos >> 1, qc = pos & 1;        // quadrant: rows qr*128, cols qc*64
    const int g = l >> 4, c = l & 15;

    const int gx = gridDim.x;                     // 32 col-tiles
    const int lin = blockIdx.y * gx + blockIdx.x;
    const int cpx = (gx * gridDim.y) >> 3;        // 512/8 = 64
    const int swz = (lin & 7) * cpx + (lin >> 3);
    const int row0 = (swz / gx) * 256, col0 = (swz % gx) * 128;

    // staging (v10 scheme): lane l -> row sr=l>>3, global chunk (l&7)^sr pre-swizzle.
    // A: wave w rows w*32..+31 (4 instances x 8 rows); B: wave w rows w*16..+15 (2 inst).
    const int sr = l >> 3;
    const int swc = (((l & 7) ^ sr) * 8);
    const unsigned short* aSr = A  + (size_t)(row0 + w*32 + sr) * K + swc;
    const unsigned short* bSr = BT + (size_t)(col0 + w*16 + sr) * K + swc;

    f32x4 acc[8][4];
#pragma unroll
    for (int m = 0; m < 8; ++m)
#pragma unroll
        for (int n = 0; n < 4; ++n) acc[m][n] = f32x4{0.f, 0.f, 0.f, 0.f};

    auto stage = [&](int kt, int bo) {             // 6 GLDS per wave
        const size_t ko = (size_t)kt * 64;
#pragma unroll
        for (int i = 0; i < 4; ++i)
            GLDS(aSr + ko + (size_t)(i*8) * K, base + bo + w*4096 + i*1024);
#pragma unroll
        for (int i = 0; i < 2; ++i)
            GLDS(bSr + ko + (size_t)(i*8) * K, base + bo + 32768 + w*2048 + i*1024);
    };
    // one K-half of one 64-k tile: 12 ds_read_b128, 32 MFMA per wave
    auto compute = [&](int bo) {
        const int chb = ((kh*4 + g) ^ (c & 7)) * 16;
        bf16x8 af[8], bfr[4];
#pragma unroll
        for (int m = 0; m < 8; ++m)
            af[m] = *(const bf16x8*)(base + bo + (qr*128 + m*16 + c) * 128 + chb);
#pragma unroll
        for (int n = 0; n < 4; ++n)
            bfr[n] = *(const bf16x8*)(base + bo + 32768 + (qc*64 + n*16 + c) * 128 + chb);
        __builtin_amdgcn_s_setprio(1);
#pragma unroll
        for (int m = 0; m < 8; ++m)
#pragma unroll
            for (int n = 0; n < 4; ++n)
                acc[m][n] = __builtin_amdgcn_mfma_f32_16x16x32_bf16(af[m], bfr[n], acc[m][n], 0, 0, 0);
        __builtin_amdgcn_s_setprio(0);
    };

    const int nkt = K >> 6;                        // 16
    stage(0, 0);
    stage(1, 49152);
    for (int kt = 0; kt < nkt; ++kt) {
        const int bo = (kt % 3) * 49152;
        if (kt + 1 < nkt) asm volatile("s_waitcnt vmcnt(6)" ::: "memory");  // waits stage(kt)
        else              asm volatile("s_waitcnt vmcnt(0)" ::: "memory");
        __builtin_amdgcn_s_barrier();              // ONE barrier per tile
        if (kt + 2 < nkt) stage(kt + 2, ((kt + 2) % 3) * 49152);   // AFTER barrier: 3-buf safe
        compute(bo);
    }

    // ---- K-half combine: kh=1 deposits partials into LDS, kh=0 adds + bias + relu ----
    asm volatile("s_waitcnt lgkmcnt(0)" ::: "memory");
    __builtin_amdgcn_s_barrier();
    if (kh) {
#pragma unroll
        for (int m = 0; m < 8; ++m)
#pragma unroll
            for (int n = 0; n < 4; ++n)
                *(f32x4*)(base + (((pos*32 + m*4 + n) * 64) + l) * 16) = acc[m][n];
    }
    asm volatile("s_waitcnt lgkmcnt(0)" ::: "memory");
    __builtin_amdgcn_s_barrier();

    if (!kh) {
#pragma unroll
        for (int m = 0; m < 8; ++m) {
            const int rb = row0 + qr*128 + m*16 + g*4;
#pragma unroll
            for (int n = 0; n < 4; ++n) {
                const f32x4 part = *(const f32x4*)(base + (((pos*32 + m*4 + n) * 64) + l) * 16);
                const int col = col0 + qc*64 + n*16 + c;
                const float bv = bias[col];
#pragma unroll
                for (int j = 0; j < 4; ++j) {
                    float v = fmaxf(acc[m][n][j] + part[j] + bv, 0.f);
                    C[(size_t)(rb + j) * N + col] = f2bf(v);
                }
            }
        }
    }
}

// ---------------- bf16 TN GEMM vQKV: 256x192 tile -> grid (16,16) = 256 wgs (R10-verified) --
__global__ __launch_bounds__(512) __attribute__((amdgpu_waves_per_eu(2, 2)))
void k_gemm_qkv(
    const unsigned short* __restrict__ A,
    const unsigned short* __restrict__ BT,
    unsigned short* __restrict__ Qo,
    unsigned short* __restrict__ Ko,
    unsigned short* __restrict__ Vo,
    int K)
{
    __shared__ uint4 ldsv[8192];       // 128 KiB: 2 bufs x [A 32K | B 24K] (+pad)
    char* base = (char*)ldsv;
    const int t = threadIdx.x, l = t & 63, w = t >> 6;
    const int wr = w >> 2, wc = w & 3;            // wave tile: rows wr*128, cols wc*48
    const int g = l >> 4, c = l & 15;

    const int gx = gridDim.x;                     // 16
    const int lin = blockIdx.y * gx + blockIdx.x;
    const int cpx = (gx * gridDim.y) >> 3;
    const int swz = (lin & 7) * cpx + (lin >> 3);
    const int row0 = (swz / gx) * 256, col0 = (swz % gx) * 192;

    const int sr = l >> 3, sc = l & 7;
    const int swk = (sc ^ sr) * 8;
    const unsigned short* aSr = A  + (size_t)(row0 + w*32 + sr) * K + swk;
    const unsigned short* bSr = BT + (size_t)(col0 + w*24 + sr) * K + swk;

    f32x4 acc[8][3];
#pragma unroll
    for (int m = 0; m < 8; ++m)
#pragma unroll
        for (int n = 0; n < 3; ++n) acc[m][n] = f32x4{0.f, 0.f, 0.f, 0.f};

    auto stage = [&](int kt, int bo) {             // 7 GLDS per wave
        const size_t ko = (size_t)kt * 64;
#pragma unroll
        for (int i = 0; i < 4; ++i)
            GLDS(aSr + ko + (size_t)(i*8) * K, base + bo + w*4096 + i*1024);
#pragma unroll
        for (int i = 0; i < 3; ++i)
            GLDS(bSr + ko + (size_t)(i*8) * K, base + bo + 32768 + w*3072 + i*1024);
    };

    const int nkt = K >> 6;                        // 16
    stage(0, 0);
    asm volatile("s_waitcnt vmcnt(0)" ::: "memory");
    __builtin_amdgcn_s_barrier();
    int bufo = 0;
    for (int kt = 0; kt < nkt; ++kt) {
        if (kt + 1 < nkt) stage(kt + 1, bufo ^ 65536);
        bf16x8 bfr[3][2];
#pragma unroll
        for (int n = 0; n < 3; ++n)
#pragma unroll
            for (int ks = 0; ks < 2; ++ks) {
                const int r = wc*48 + n*16 + c;
                bfr[n][ks] = *(const bf16x8*)(base + bufo + 32768 + r*128
                                              + (((ks*4 + g) ^ (c & 7)) * 16));
            }
#pragma unroll
        for (int p = 0; p < 4; ++p) {
            bf16x8 af[2][2];
#pragma unroll
            for (int mi = 0; mi < 2; ++mi)
#pragma unroll
                for (int ks = 0; ks < 2; ++ks) {
                    const int r = wr*128 + (p*2 + mi)*16 + c;
                    af[mi][ks] = *(const bf16x8*)(base + bufo + r*128
                                                  + (((ks*4 + g) ^ (c & 7)) * 16));
                }
            __builtin_amdgcn_s_setprio(1);
#pragma unroll
            for (int ks = 0; ks < 2; ++ks)
#pragma unroll
                for (int mi = 0; mi < 2; ++mi)
#pragma unroll
                    for (int n = 0; n < 3; ++n)
                        acc[p*2 + mi][n] = __builtin_amdgcn_mfma_f32_16x16x32_bf16(
                            af[mi][ks], bfr[n][ks], acc[p*2 + mi][n], 0, 0, 0);
            __builtin_amdgcn_s_setprio(0);
        }
        if (kt + 1 < nkt) {
            asm volatile("s_waitcnt vmcnt(0)" ::: "memory");
            __builtin_amdgcn_s_barrier();
            bufo ^= 65536;
        }
    }

    // epilogue: QKV split; C/D layout col = lane&15, row = (lane>>4)*4 + j
#pragma unroll
    for (int m = 0; m < 8; ++m) {
        const int rb = row0 + wr*128 + m*16 + g*4;
        const int b  = rb >> 11;           // SEQ = 2048
        const int q0 = rb & 2047;
#pragma unroll
        for (int n = 0; n < 3; ++n) {
            const int col = col0 + wc*48 + n*16 + c;
            const int hh  = col / 192;
            const int rem = col - hh * 192;
            const int tt  = rem >> 6;
            const int d   = rem & 63;
            const int bhh = b * HEADS + hh;
            if (tt == 2) {
                const int st_e = q0 >> 6, kk = q0 & 63;
                const int f_e  = (d >> 5) * 4 + (kk >> 4);
                const int ln_e = ((kk >> 3) & 1) * 32 + (d & 31);
                const int e0   = kk & 7;
                ushort4 o;
                o.x = f2bf(acc[m][n][0]); o.y = f2bf(acc[m][n][1]);
                o.z = f2bf(acc[m][n][2]); o.w = f2bf(acc[m][n][3]);
                *(ushort4*)(Vo + (size_t)bhh * (SEQ*HDIM) + st_e*4096 + f_e*512 + ln_e*8 + e0) = o;
            } else if (tt == 1) {
                const int st_e = q0 >> 6;
                const int f_e  = ((q0 >> 5) & 1) * 4 + (d >> 4);
                const int lq_e = q0 & 31;
                const int ln_b = ((d >> 3) & 1) * 32;
                const int e_e  = d & 7;
                unsigned short* dst = Ko + (size_t)bhh * (SEQ*HDIM) + st_e*4096 + f_e*512
                                         + (ln_b + lq_e)*8 + e_e;
#pragma unroll
                for (int j = 0; j < 4; ++j)
                    dst[j*8] = f2bf(acc[m][n][j]);
            } else {
                unsigned short* dst = Qo + ((size_t)bhh * SEQ + q0) * HDIM + d;
#pragma unroll
                for (int j = 0; j < 4; ++j)
                    dst[(size_t)j * HDIM] = f2bf(acc[m][n][j]);
            }
        }
    }
}

// ---------------- causal flash attention, 32x32 swapped, fragment-major K/V ----------------
__global__ __launch_bounds__(512) __attribute__((amdgpu_waves_per_eu(2, 2)))
void k_attention(
    const unsigned short* __restrict__ Qb,
    const unsigned short* __restrict__ Kf,
    const unsigned short* __restrict__ Vf,
    unsigned short* __restrict__ out)
{
    const int t = threadIdx.x, l = t & 63, w = t >> 6;
    const int lq = l & 31, hi = l >> 5;
    const int bid = blockIdx.x;
    const int sbid = (bid & 7) * 32 + (bid >> 3);
    const int bh = sbid >> 3, j = sbid & 7;
    const int qb = (w < 4) ? (4*j + w) : (63 - 4*j - (w - 4));
    const int q  = qb * 32 + lq;

    const unsigned short* Qh  = Qb + (size_t)bh * SEQ * HDIM;
    const unsigned short* Kfh = Kf + (size_t)bh * SEQ * HDIM + l*8;
    const unsigned short* Vfh = Vf + (size_t)bh * SEQ * HDIM + l*8;

    const bf16x8 qf0 = *(const bf16x8*)(Qh + (size_t)q * HDIM      + hi*8);
    const bf16x8 qf1 = *(const bf16x8*)(Qh + (size_t)q * HDIM + 16 + hi*8);
    const bf16x8 qf2 = *(const bf16x8*)(Qh + (size_t)q * HDIM + 32 + hi*8);
    const bf16x8 qf3 = *(const bf16x8*)(Qh + (size_t)q * HDIM + 48 + hi*8);

    f32x16 oT0, oT1;
#pragma unroll
    for (int i = 0; i < 16; ++i) { oT0[i] = 0.f; oT1[i] = 0.f; }
    float lacc0 = 0.f, lacc1 = 0.f, lacc2 = 0.f, lacc3 = 0.f;
    const float kSc = 0.18033688011112042f;   // 0.125 * log2(e)
    const int nst = (qb >> 1) + 1;

    bf16x8 kA0, kA1, kA2, kA3, kA4, kA5, kA6, kA7;
    bf16x8 kB0, kB1, kB2, kB3, kB4, kB5, kB6, kB7;

#define LOADK(stv, KF) do {                                                     \
    const unsigned short* kp_ = Kfh + (size_t)(stv) * 4096;                     \
    KF##0 = *(const bf16x8*)(kp_ +    0); KF##1 = *(const bf16x8*)(kp_ +  512); \
    KF##2 = *(const bf16x8*)(kp_ + 1024); KF##3 = *(const bf16x8*)(kp_ + 1536); \
    KF##4 = *(const bf16x8*)(kp_ + 2048); KF##5 = *(const bf16x8*)(kp_ + 2560); \
    KF##6 = *(const bf16x8*)(kp_ + 3072); KF##7 = *(const bf16x8*)(kp_ + 3584); \
} while (0)

#define STEP(stv, KF) do {                                                      \
    const int kv0_ = (stv) * 64;                                                \
    const unsigned short* vp_ = Vfh + (size_t)(stv) * 4096;                     \
    bf16x8 vf0_ = *(const bf16x8*)(vp_ +    0), vf1_ = *(const bf16x8*)(vp_ +  512); \
    bf16x8 vf2_ = *(const bf16x8*)(vp_ + 1024), vf3_ = *(const bf16x8*)(vp_ + 1536); \
    bf16x8 vf4_ = *(const bf16x8*)(vp_ + 2048), vf5_ = *(const bf16x8*)(vp_ + 2560); \
    bf16x8 vf6_ = *(const bf16x8*)(vp_ + 3072), vf7_ = *(const bf16x8*)(vp_ + 3584); \
    f32x16 sA_, sB_;                                                            \
    _Pragma("unroll")                                                           \
    for (int i = 0; i < 16; ++i) { sA_[i] = 0.f; sB_[i] = 0.f; }               \
    __builtin_amdgcn_s_setprio(1);                                              \
    sA_ = __builtin_amdgcn_mfma_f32_32x32x16_bf16(KF##0, qf0, sA_, 0, 0, 0);    \
    sA_ = __builtin_amdgcn_mfma_f32_32x32x16_bf16(KF##1, qf1, sA_, 0, 0, 0);    \
    sA_ = __builtin_amdgcn_mfma_f32_32x32x16_bf16(KF##2, qf2, sA_, 0, 0, 0);    \
    sA_ = __builtin_amdgcn_mfma_f32_32x32x16_bf16(KF##3, qf3, sA_, 0, 0, 0);    \
    sB_ = __builtin_amdgcn_mfma_f32_32x32x16_bf16(KF##4, qf0, sB_, 0, 0, 0);    \
    sB_ = __builtin_amdgcn_mfma_f32_32x32x16_bf16(KF##5, qf1, sB_, 0, 0, 0);    \
    sB_ = __builtin_amdgcn_mfma_f32_32x32x16_bf16(KF##6, qf2, sB_, 0, 0, 0);    \
    sB_ = __builtin_amdgcn_mfma_f32_32x32x16_bf16(KF##7, qf3, sB_, 0, 0, 0);    \
    __builtin_amdgcn_s_setprio(0);                                              \
    float p_[32];                                                               \
    if ((stv) == nst - 1) {                                                     \
        _Pragma("unroll")                                                       \
        for (int r = 0; r < 16; ++r) {                                          \
            const int key_ = kv0_ + (r & 3) + 8*(r >> 2) + 4*hi;                \
            p_[r]      = (key_      <= q) ? fexp2(sA_[r] * kSc) : 0.f;          \
            p_[16 + r] = (key_ + 32 <= q) ? fexp2(sB_[r] * kSc) : 0.f;          \
        }                                                                       \
    } else {                                                                    \
        _Pragma("unroll")                                                       \
        for (int r = 0; r < 16; ++r) {                                          \
            p_[r]      = fexp2(sA_[r] * kSc);                                   \
            p_[16 + r] = fexp2(sB_[r] * kSc);                                   \
        }                                                                       \
    }                                                                           \
    _Pragma("unroll")                                                           \
    for (int i = 0; i < 32; i += 4) {                                           \
        lacc0 += p_[i]; lacc1 += p_[i+1]; lacc2 += p_[i+2]; lacc3 += p_[i+3];   \
    }                                                                           \
    bf16x8 pa_[4];                                                              \
    _Pragma("unroll")                                                           \
    for (int ks = 0; ks < 4; ++ks) {                                            \
        const int b8_ = ks * 8;                                                 \
        uint32x2 rA_ = __builtin_amdgcn_permlane32_swap(                        \
            cvtpk_bf16(p_[b8_+0], p_[b8_+1]), cvtpk_bf16(p_[b8_+4], p_[b8_+5]), false, false); \
        uint32x2 rB_ = __builtin_amdgcn_permlane32_swap(                        \
            cvtpk_bf16(p_[b8_+2], p_[b8_+3]), cvtpk_bf16(p_[b8_+6], p_[b8_+7]), false, false); \
        union { uint32_t u[4]; bf16x8 v; } pk_;                                 \
        pk_.u[0] = rA_[0]; pk_.u[1] = rB_[0]; pk_.u[2] = rA_[1]; pk_.u[3] = rB_[1]; \
        pa_[ks] = pk_.v;                                                        \
    }                                                                           \
    __builtin_amdgcn_s_setprio(1);                                              \
    oT0 = __builtin_amdgcn_mfma_f32_32x32x16_bf16(vf0_, pa_[0], oT0, 0, 0, 0);  \
    oT0 = __builtin_amdgcn_mfma_f32_32x32x16_bf16(vf1_, pa_[1], oT0, 0, 0, 0);  \
    oT0 = __builtin_amdgcn_mfma_f32_32x32x16_bf16(vf2_, pa_[2], oT0, 0, 0, 0);  \
    oT0 = __builtin_amdgcn_mfma_f32_32x32x16_bf16(vf3_, pa_[3], oT0, 0, 0, 0);  \
    oT1 = __builtin_amdgcn_mfma_f32_32x32x16_bf16(vf4_, pa_[0], oT1, 0, 0, 0);  \
    oT1 = __builtin_amdgcn_mfma_f32_32x32x16_bf16(vf5_, pa_[1], oT1, 0, 0, 0);  \
    oT1 = __builtin_amdgcn_mfma_f32_32x32x16_bf16(vf6_, pa_[2], oT1, 0, 0, 0);  \
    oT1 = __builtin_amdgcn_mfma_f32_32x32x16_bf16(vf7_, pa_[3], oT1, 0, 0, 0);  \
    __builtin_amdgcn_s_setprio(0);                                              \
} while (0)

    LOADK(0, kA);
    int st = 0;
    for (;;) {
        if (st + 1 < nst) LOADK(st + 1, kB);
        STEP(st, kA);
        if (++st >= nst) break;
        if (st + 1 < nst) LOADK(st + 1, kA);
        STEP(st, kB);
        if (++st >= nst) break;
    }
#undef LOADK
#undef STEP

    float lsum = (lacc0 + lacc1) + (lacc2 + lacc3);
    lsum += __shfl_xor(lsum, 32, 64);
    const float inv = 1.f / lsum;
    unsigned short* ob = out + ((size_t)bh * SEQ + q) * HDIM;
#pragma unroll
    for (int m2 = 0; m2 < 4; ++m2) {
        ushort4 o0, o1;
        o0.x = f2bf(oT0[m2*4+0] * inv); o0.y = f2bf(oT0[m2*4+1] * inv);
        o0.z = f2bf(oT0[m2*4+2] * inv); o0.w = f2bf(oT0[m2*4+3] * inv);
        o1.x = f2bf(oT1[m2*4+0] * inv); o1.y = f2bf(oT1[m2*4+1] * inv);
        o1.z = f2bf(oT1[m2*4+2] * inv); o1.w = f2bf(oT1[m2*4+3] * inv);
        *(ushort4*)(ob +      m2*8 + hi*4) = o0;
        *(ushort4*)(ob + 32 + m2*8 + hi*4) = o1;
    }
}

// ---------------- host launcher ----------------
extern "C" void kernel_launch(void* const* d_in, const int* in_sizes, int n_in,
                              void* d_out, int out_size, void* d_ws, size_t ws_size,
                              hipStream_t stream)
{
    (void)in_sizes; (void)n_in; (void)out_size; (void)ws_size;
    const float* x      = (const float*)d_in[0];
    const float* w_qkv  = (const float*)d_in[1];
    const float* w_proj = (const float*)d_in[2];
    const float* b_proj = (const float*)d_in[3];
    const float* w1     = (const float*)d_in[4];
    const float* b1     = (const float*)d_in[5];
    const float* w2     = (const float*)d_in[6];
    const float* b2     = (const float*)d_in[7];
    const float* g1     = (const float*)d_in[8];
    const float* be1    = (const float*)d_in[9];
    const float* g2     = (const float*)d_in[10];
    const float* be2    = (const float*)d_in[11];

    char* ws = (char*)d_ws;
    size_t o = 0;
    auto take = [&](size_t bytes) -> char* {
        char* p = ws + o;
        o += (bytes + 255) & ~(size_t)255;
        return p;
    };
    unsigned short* wqkvT  = (unsigned short*)take(3072ull * 1024 * 2);
    unsigned short* wprojT = (unsigned short*)take(1024ull * 1024 * 2);
    unsigned short* w1T    = (unsigned short*)take(4096ull * 1024 * 2);
    unsigned short* w2T    = (unsigned short*)take(1024ull * 4096 * 2);
    unsigned short* h      = (unsigned short*)take(4096ull * 1024 * 2);   // LN out (reused)
    unsigned short* Qb     = (unsigned short*)take(4096ull * 1024 * 2);
    unsigned short* Kfb    = (unsigned short*)take(4096ull * 1024 * 2);
    unsigned short* Vfb    = (unsigned short*)take(4096ull * 1024 * 2);
    unsigned short* attno  = (unsigned short*)take(4096ull * 1024 * 2);
    float*          x2     = (float*)take(4096ull * 1024 * 4);
    unsigned short* f1     = Qb;   // alias: Q/Kf/Vf/attno (32MB) dead before FF1 writes

    // prep: all four weight transposes + LN1 in ONE launch
    k_prep<<<16384, 256, 0, stream>>>(
        w_qkv, w_proj, w1, w2, wqkvT, wprojT, w1T, w2T, x, g1, be1, h);

    // QKV GEMM (256x192 tiles, 256 wgs = full CU fill) -> Q / Kf / Vf
    k_gemm_qkv<<<dim3(16, 16), 512, 0, stream>>>(h, wqkvT, Qb, Kfb, Vfb, 1024);
    // attention: 256 blocks x 512 threads (8 waves, balanced qb pairing)
    k_attention<<<256, 512, 0, stream>>>(Qb, Kfb, Vfb, attno);
    // proj + bias + residual(x) -> x2 (fp32)  [128^2 v10: N=1024, K=1024]
    k_gemm_bt<5, float><<<dim3(8, 32), 512, 0, stream>>>(
        attno, wprojT, b_proj, x, x2, ROWS, 1024, 1024);
    // LN2
    k_layernorm<<<4096, 256, 0, stream>>>(x2, g2, be2, h);
    // FF1 + bias + relu -> bf16 (256x128 tiles, quadrant x K-half waves, 3-buf)
    k_gemm_ff1<<<dim3(32, 16), 512, 0, stream>>>(h, w1T, b1, f1, 4096, 1024);
    // FF2 + bias + residual(x2) -> d_out (fp32)  [128^2 v10: N=1024, K=4096]
    k_gemm_bt<5, float><<<dim3(8, 32), 512, 0, stream>>>(
        f1, w2T, b2, x2, (float*)d_out, ROWS, 1024, 4096);
}

// Round 12
// 176.261 us; speedup vs baseline: 1.0469x; 1.0469x over previous
//
#include <hip/hip_runtime.h>
#include <cstdint>

#define EMBED 1024
#define HEADS 16
#define HDIM  64
#define SEQ   2048
#define BATCH 2
#define ROWS  (BATCH*SEQ)   // 4096

typedef __bf16 bf16x8 __attribute__((ext_vector_type(8)));
typedef float  f32x4  __attribute__((ext_vector_type(4)));
typedef float  f32x16 __attribute__((ext_vector_type(16)));
typedef unsigned int uint32x2 __attribute__((ext_vector_type(2)));

__device__ __forceinline__ unsigned short f2bf(float f) {
    union { float f; uint32_t u; } v; v.f = f;
    uint32_t r = v.u + 0x7fffu + ((v.u >> 16) & 1u);
    return (unsigned short)(r >> 16);
}

__device__ __forceinline__ uint32_t cvtpk_bf16(float lo, float hi) {
    uint32_t r;
    asm("v_cvt_pk_bf16_f32 %0, %1, %2" : "=v"(r) : "v"(lo), "v"(hi));
    return r;
}

// hardware 2^x (quarter-rate, 1 inst; exp2f without -ffast-math is a libm call)
__device__ __forceinline__ float fexp2(float x) {
    float r;
    asm("v_exp_f32 %0, %1" : "=v"(r) : "v"(x));
    return r;
}

#define GLDS(src, dst) __builtin_amdgcn_global_load_lds( \
    (const __attribute__((address_space(1))) uint32_t*)(src), \
    (__attribute__((address_space(3))) uint32_t*)(dst), 16, 0, 0)

// ---------------- fused prep: ALL FOUR weight transposes + LN1, one launch ----------------
__global__ __launch_bounds__(256) void k_prep(
    const float* __restrict__ w_qkv, const float* __restrict__ w_proj,
    const float* __restrict__ w1,    const float* __restrict__ w2,
    unsigned short* __restrict__ wqkvT, unsigned short* __restrict__ wprojT,
    unsigned short* __restrict__ w1T,   unsigned short* __restrict__ w2T,
    const float* __restrict__ x, const float* __restrict__ g1,
    const float* __restrict__ be1, unsigned short* __restrict__ h)
{
    int b = blockIdx.x;
    if (b >= 12288) {
        // ---- LN1 ----
        const int row = b - 12288, t = threadIdx.x;
        float4 v = ((const float4*)(x + (size_t)row * EMBED))[t];
        float s = v.x + v.y + v.z + v.w;
        float q = v.x*v.x + v.y*v.y + v.z*v.z + v.w*v.w;
#pragma unroll
        for (int off = 32; off >= 1; off >>= 1) {
            s += __shfl_xor(s, off, 64);
            q += __shfl_xor(q, off, 64);
        }
        __shared__ float ss[4], sq[4];
        if ((t & 63) == 0) { ss[t >> 6] = s; sq[t >> 6] = q; }
        __syncthreads();
        s = ss[0] + ss[1] + ss[2] + ss[3];
        q = sq[0] + sq[1] + sq[2] + sq[3];
        const float mu  = s * (1.0f / EMBED);
        const float var = q * (1.0f / EMBED) - mu * mu;
        const float rs  = rsqrtf(var + 1e-5f);
        float4 gv = ((const float4*)g1)[t];
        float4 bv = ((const float4*)be1)[t];
        ushort4 o;
        o.x = f2bf((v.x - mu) * rs * gv.x + bv.x);
        o.y = f2bf((v.y - mu) * rs * gv.y + bv.y);
        o.z = f2bf((v.z - mu) * rs * gv.z + bv.z);
        o.w = f2bf((v.w - mu) * rs * gv.w + bv.w);
        ((ushort4*)(h + (size_t)row * EMBED))[t] = o;
        return;
    }
    const float* in; unsigned short* out; int N, K, nx;
    if (b < 3072)      {           in = w_qkv;  out = wqkvT;  K = 1024; N = 3072; nx = 96; }
    else if (b < 4096) { b -= 3072; in = w_proj; out = wprojT; K = 1024; N = 1024; nx = 32; }
    else if (b < 8192) { b -= 4096; in = w1;     out = w1T;    K = 1024; N = 4096; nx = 128; }
    else               { b -= 8192; in = w2;     out = w2T;    K = 4096; N = 1024; nx = 32; }
    const int n0 = (b % nx) * 32, k0 = (b / nx) * 32;

    __shared__ float tile[32][33];
    const int tx = threadIdx.x & 31, ty = threadIdx.x >> 5;
#pragma unroll
    for (int r = 0; r < 4; ++r)
        tile[ty + 8*r][tx] = in[(size_t)(k0 + ty + 8*r) * N + n0 + tx];
    __syncthreads();
#pragma unroll
    for (int r = 0; r < 4; ++r)
        out[(size_t)(n0 + ty + 8*r) * K + k0 + tx] = f2bf(tile[tx][ty + 8*r]);
}

// ---------------- LayerNorm: fp32 in -> bf16 out (LN2) ----------------
__global__ __launch_bounds__(256) void k_layernorm(
    const float* __restrict__ x, const float* __restrict__ g, const float* __restrict__ b,
    unsigned short* __restrict__ h)
{
    const int row = blockIdx.x, t = threadIdx.x;
    float4 v = ((const float4*)(x + (size_t)row * EMBED))[t];
    float s = v.x + v.y + v.z + v.w;
    float q = v.x*v.x + v.y*v.y + v.z*v.z + v.w*v.w;
#pragma unroll
    for (int off = 32; off >= 1; off >>= 1) {
        s += __shfl_xor(s, off, 64);
        q += __shfl_xor(q, off, 64);
    }
    __shared__ float ss[4], sq[4];
    if ((t & 63) == 0) { ss[t >> 6] = s; sq[t >> 6] = q; }
    __syncthreads();
    s = ss[0] + ss[1] + ss[2] + ss[3];
    q = sq[0] + sq[1] + sq[2] + sq[3];
    const float mu  = s * (1.0f / EMBED);
    const float var = q * (1.0f / EMBED) - mu * mu;
    const float rs  = rsqrtf(var + 1e-5f);
    float4 gv = ((const float4*)g)[t];
    float4 bv = ((const float4*)b)[t];
    ushort4 o;
    o.x = f2bf((v.x - mu) * rs * gv.x + bv.x);
    o.y = f2bf((v.y - mu) * rs * gv.y + bv.y);
    o.z = f2bf((v.z - mu) * rs * gv.z + bv.z);
    o.w = f2bf((v.w - mu) * rs * gv.w + bv.w);
    ((ushort4*)(h + (size_t)row * EMBED))[t] = o;
}

// ---------------- bf16 TN GEMM v10: 128x128, quadrant waves, 4-BUF SINGLE-BARRIER loop -----
// R8-verified: -3.7us on FF2 vs 2-barrier. FLAGS: 1=bias, 2=relu, 4=residual(fp32).
template<int FLAGS, typename OutT>
__global__ __launch_bounds__(512) void k_gemm_bt(
    const unsigned short* __restrict__ A,
    const unsigned short* __restrict__ BT,
    const float* __restrict__ bias,
    const float* __restrict__ resid,
    OutT* __restrict__ C,
    int M, int N, int K)
{
    __shared__ uint4 ldsv[8192];       // 128 KiB: 4 bufs x [A 16K | B 16K]
    char* base = (char*)ldsv;
    char* aL = base;
    char* bL = base + 16384;
    const int t = threadIdx.x, l = t & 63, w = t >> 6;
    const int pos = w & 3, kh = w >> 2;
    const int qr = pos >> 1, qc = pos & 1;
    const int g = l >> 4, c = l & 15;

    const int gx = gridDim.x;
    const int lin = blockIdx.y * gx + blockIdx.x;
    const int cpx = (gx * gridDim.y) >> 3;
    const int swz = (lin & 7) * cpx + (lin >> 3);
    const int row0 = (swz / gx) * 128, col0 = (swz % gx) * 128;

    const int swc = (((l & 7) ^ (l >> 3)) * 8);
    const int rA0 = w*16 + (l >> 3), rA1 = rA0 + 8;
    const unsigned short* aS0 = A  + (size_t)(row0 + rA0) * K + swc;
    const unsigned short* aS1 = A  + (size_t)(row0 + rA1) * K + swc;
    const unsigned short* bS0 = BT + (size_t)(col0 + rA0) * K + swc;
    const unsigned short* bS1 = BT + (size_t)(col0 + rA1) * K + swc;
    const int dst0 = w * 2048, dst1 = w * 2048 + 1024;

    f32x4 acc[4][4];
#pragma unroll
    for (int m = 0; m < 4; ++m)
#pragma unroll
        for (int n = 0; n < 4; ++n) acc[m][n] = f32x4{0.f, 0.f, 0.f, 0.f};

    auto stage = [&](int kt, int bo) {
        const size_t ko = (size_t)kt * 64;
        GLDS(aS0 + ko, aL + bo + dst0);
        GLDS(aS1 + ko, aL + bo + dst1);
        GLDS(bS0 + ko, bL + bo + dst0);
        GLDS(bS1 + ko, bL + bo + dst1);
    };
    auto compute = [&](int bo) {
        const int chb = ((kh*4 + g) ^ (c & 7)) * 16;
        bf16x8 af[4], bfr[4];
#pragma unroll
        for (int m = 0; m < 4; ++m)
            af[m] = *(const bf16x8*)(aL + bo + (qr*64 + m*16 + c) * 128 + chb);
#pragma unroll
        for (int n = 0; n < 4; ++n)
            bfr[n] = *(const bf16x8*)(bL + bo + (qc*64 + n*16 + c) * 128 + chb);
        __builtin_amdgcn_s_setprio(1);
#pragma unroll
        for (int m = 0; m < 4; ++m)
#pragma unroll
            for (int n = 0; n < 4; ++n)
                acc[m][n] = __builtin_amdgcn_mfma_f32_16x16x32_bf16(af[m], bfr[n], acc[m][n], 0, 0, 0);
        __builtin_amdgcn_s_setprio(0);
    };

    const int nkt = K >> 6;
    stage(0, 0);
    stage(1, 32768);
    for (int kt = 0; kt < nkt; ++kt) {
        const int bo = (kt & 3) * 32768;
        if (kt + 2 < nkt) {
            stage(kt + 2, ((kt + 2) & 3) * 32768);
            asm volatile("s_waitcnt vmcnt(8)" ::: "memory");
        } else if (kt + 1 < nkt) {
            asm volatile("s_waitcnt vmcnt(4)" ::: "memory");
        } else {
            asm volatile("s_waitcnt vmcnt(0)" ::: "memory");
        }
        __builtin_amdgcn_s_barrier();
        compute(bo);
    }

    asm volatile("s_waitcnt lgkmcnt(0)" ::: "memory");
    __builtin_amdgcn_s_barrier();
    if (kh) {
#pragma unroll
        for (int m = 0; m < 4; ++m)
#pragma unroll
            for (int n = 0; n < 4; ++n)
                *(f32x4*)(base + (((pos*16 + m*4 + n) * 64) + l) * 16) = acc[m][n];
    }
    asm volatile("s_waitcnt lgkmcnt(0)" ::: "memory");
    __builtin_amdgcn_s_barrier();

    if (!kh) {
#pragma unroll
        for (int m = 0; m < 4; ++m) {
            const int rb = row0 + qr*64 + m*16 + g*4;
#pragma unroll
            for (int n = 0; n < 4; ++n) {
                const f32x4 part = *(const f32x4*)(base + (((pos*16 + m*4 + n) * 64) + l) * 16);
                const int col = col0 + qc*64 + n*16 + c;
                float bv = 0.f;
                if constexpr ((FLAGS & 1) != 0) bv = bias[col];
#pragma unroll
                for (int j = 0; j < 4; ++j) {
                    float v = acc[m][n][j] + part[j] + bv;
                    if constexpr ((FLAGS & 2) != 0) v = fmaxf(v, 0.f);
                    if constexpr ((FLAGS & 4) != 0) v += resid[(size_t)(rb + j) * N + col];
                    if constexpr (sizeof(OutT) == 2) C[(size_t)(rb + j) * N + col] = (OutT)f2bf(v);
                    else                             C[(size_t)(rb + j) * N + col] = v;
                }
            }
        }
    }
}

// ---------------- bf16 TN GEMM v7: 256x256 tile, BK=32, 4-BUF SINGLE-BARRIER (FF1) --------
// R9/R10-measured best for FF1 (~35us). R11's 256x128-quadrant variant regressed to 47us
// (144KB LDS -> 1 wg/CU -> two sequential device passes); reverted. FLAGS: 1=bias, 2=relu.
template<int FLAGS, typename OutT>
__global__ __launch_bounds__(512) __attribute__((amdgpu_waves_per_eu(2, 2)))
void k_gemm256(
    const unsigned short* __restrict__ A,
    const unsigned short* __restrict__ BT,
    const float* __restrict__ bias,
    OutT* __restrict__ C,
    int M, int N, int K)
{
    __shared__ uint4 ldsv[8192];       // 128 KiB: 4 bufs x [A 16K | B 16K]
    char* base = (char*)ldsv;
    const int t = threadIdx.x, l = t & 63, w = t >> 6;
    const int wr = w >> 2, wc = w & 3;
    const int g = l >> 4, c = l & 15;

    const int gx = gridDim.x;
    const int lin = blockIdx.y * gx + blockIdx.x;
    const int cpx = (gx * gridDim.y) >> 3;
    const int swz = (lin & 7) * cpx + (lin >> 3);
    const int row0 = (swz / gx) * 256, col0 = (swz % gx) * 256;

    const int srow = l >> 2;
    const int sch  = (l & 3) ^ ((l >> 3) & 3);
    const unsigned short* aS0 = A  + (size_t)(row0 + w*32 +      srow) * K + sch*8;
    const unsigned short* aS1 = A  + (size_t)(row0 + w*32 + 16 + srow) * K + sch*8;
    const unsigned short* bS0 = BT + (size_t)(col0 + w*32 +      srow) * K + sch*8;
    const unsigned short* bS1 = BT + (size_t)(col0 + w*32 + 16 + srow) * K + sch*8;
    const int dA0 = w*2048, dA1 = w*2048 + 1024;

    f32x4 acc[8][4];
#pragma unroll
    for (int m = 0; m < 8; ++m)
#pragma unroll
        for (int n = 0; n < 4; ++n) acc[m][n] = f32x4{0.f, 0.f, 0.f, 0.f};

    auto stage = [&](int kt, int bo) {
        const size_t ko = (size_t)kt * 32;
        GLDS(aS0 + ko, base + bo + dA0);
        GLDS(aS1 + ko, base + bo + dA1);
        GLDS(bS0 + ko, base + bo + 16384 + dA0);
        GLDS(bS1 + ko, base + bo + 16384 + dA1);
    };
    auto compute = [&](int bo) {
        const int chb = (g ^ ((c >> 1) & 3)) * 16;
        bf16x8 af[8], bfr[4];
#pragma unroll
        for (int m = 0; m < 8; ++m)
            af[m] = *(const bf16x8*)(base + bo + (wr*128 + m*16 + c) * 64 + chb);
#pragma unroll
        for (int n = 0; n < 4; ++n)
            bfr[n] = *(const bf16x8*)(base + bo + 16384 + (wc*64 + n*16 + c) * 64 + chb);
        __builtin_amdgcn_s_setprio(1);
#pragma unroll
        for (int m = 0; m < 8; ++m)
#pragma unroll
            for (int n = 0; n < 4; ++n)
                acc[m][n] = __builtin_amdgcn_mfma_f32_16x16x32_bf16(af[m], bfr[n], acc[m][n], 0, 0, 0);
        __builtin_amdgcn_s_setprio(0);
    };

    const int nkt = K >> 5;
    stage(0, 0);
    stage(1, 32768);
    for (int kt = 0; kt < nkt; ++kt) {
        const int bo = (kt & 3) * 32768;
        if (kt + 2 < nkt) {
            stage(kt + 2, ((kt + 2) & 3) * 32768);
            asm volatile("s_waitcnt vmcnt(8)" ::: "memory");
        } else if (kt + 1 < nkt) {
            asm volatile("s_waitcnt vmcnt(4)" ::: "memory");
        } else {
            asm volatile("s_waitcnt vmcnt(0)" ::: "memory");
        }
        __builtin_amdgcn_s_barrier();
        compute(bo);
    }

#pragma unroll
    for (int m = 0; m < 8; ++m) {
        const int rb = row0 + wr*128 + m*16 + g*4;
#pragma unroll
        for (int n = 0; n < 4; ++n) {
            const int col = col0 + wc*64 + n*16 + c;
            float bv = 0.f;
            if constexpr ((FLAGS & 1) != 0) bv = bias[col];
#pragma unroll
            for (int j = 0; j < 4; ++j) {
                float v = acc[m][n][j] + bv;
                if constexpr ((FLAGS & 2) != 0) v = fmaxf(v, 0.f);
                if constexpr (sizeof(OutT) == 2) C[(size_t)(rb + j) * N + col] = (OutT)f2bf(v);
                else                             C[(size_t)(rb + j) * N + col] = v;
            }
        }
    }
}

// ---------------- bf16 TN GEMM vQKV: 256x192 tile -> grid (16,16) = 256 wgs (R10-verified) --
__global__ __launch_bounds__(512) __attribute__((amdgpu_waves_per_eu(2, 2)))
void k_gemm_qkv(
    const unsigned short* __restrict__ A,
    const unsigned short* __restrict__ BT,
    unsigned short* __restrict__ Qo,
    unsigned short* __restrict__ Ko,
    unsigned short* __restrict__ Vo,
    int K)
{
    __shared__ uint4 ldsv[8192];       // 128 KiB: 2 bufs x [A 32K | B 24K] (+pad)
    char* base = (char*)ldsv;
    const int t = threadIdx.x, l = t & 63, w = t >> 6;
    const int wr = w >> 2, wc = w & 3;            // wave tile: rows wr*128, cols wc*48
    const int g = l >> 4, c = l & 15;

    const int gx = gridDim.x;                     // 16
    const int lin = blockIdx.y * gx + blockIdx.x;
    const int cpx = (gx * gridDim.y) >> 3;
    const int swz = (lin & 7) * cpx + (lin >> 3);
    const int row0 = (swz / gx) * 256, col0 = (swz % gx) * 192;

    const int sr = l >> 3, sc = l & 7;
    const int swk = (sc ^ sr) * 8;
    const unsigned short* aSr = A  + (size_t)(row0 + w*32 + sr) * K + swk;
    const unsigned short* bSr = BT + (size_t)(col0 + w*24 + sr) * K + swk;

    f32x4 acc[8][3];
#pragma unroll
    for (int m = 0; m < 8; ++m)
#pragma unroll
        for (int n = 0; n < 3; ++n) acc[m][n] = f32x4{0.f, 0.f, 0.f, 0.f};

    auto stage = [&](int kt, int bo) {             // 7 GLDS per wave
        const size_t ko = (size_t)kt * 64;
#pragma unroll
        for (int i = 0; i < 4; ++i)
            GLDS(aSr + ko + (size_t)(i*8) * K, base + bo + w*4096 + i*1024);
#pragma unroll
        for (int i = 0; i < 3; ++i)
            GLDS(bSr + ko + (size_t)(i*8) * K, base + bo + 32768 + w*3072 + i*1024);
    };

    const int nkt = K >> 6;                        // 16
    stage(0, 0);
    asm volatile("s_waitcnt vmcnt(0)" ::: "memory");
    __builtin_amdgcn_s_barrier();
    int bufo = 0;
    for (int kt = 0; kt < nkt; ++kt) {
        if (kt + 1 < nkt) stage(kt + 1, bufo ^ 65536);
        bf16x8 bfr[3][2];
#pragma unroll
        for (int n = 0; n < 3; ++n)
#pragma unroll
            for (int ks = 0; ks < 2; ++ks) {
                const int r = wc*48 + n*16 + c;
                bfr[n][ks] = *(const bf16x8*)(base + bufo + 32768 + r*128
                                              + (((ks*4 + g) ^ (c & 7)) * 16));
            }
#pragma unroll
        for (int p = 0; p < 4; ++p) {
            bf16x8 af[2][2];
#pragma unroll
            for (int mi = 0; mi < 2; ++mi)
#pragma unroll
                for (int ks = 0; ks < 2; ++ks) {
                    const int r = wr*128 + (p*2 + mi)*16 + c;
                    af[mi][ks] = *(const bf16x8*)(base + bufo + r*128
                                                  + (((ks*4 + g) ^ (c & 7)) * 16));
                }
            __builtin_amdgcn_s_setprio(1);
#pragma unroll
            for (int ks = 0; ks < 2; ++ks)
#pragma unroll
                for (int mi = 0; mi < 2; ++mi)
#pragma unroll
                    for (int n = 0; n < 3; ++n)
                        acc[p*2 + mi][n] = __builtin_amdgcn_mfma_f32_16x16x32_bf16(
                            af[mi][ks], bfr[n][ks], acc[p*2 + mi][n], 0, 0, 0);
            __builtin_amdgcn_s_setprio(0);
        }
        if (kt + 1 < nkt) {
            asm volatile("s_waitcnt vmcnt(0)" ::: "memory");
            __builtin_amdgcn_s_barrier();
            bufo ^= 65536;
        }
    }

    // epilogue: QKV split; C/D layout col = lane&15, row = (lane>>4)*4 + j
#pragma unroll
    for (int m = 0; m < 8; ++m) {
        const int rb = row0 + wr*128 + m*16 + g*4;
        const int b  = rb >> 11;           // SEQ = 2048
        const int q0 = rb & 2047;
#pragma unroll
        for (int n = 0; n < 3; ++n) {
            const int col = col0 + wc*48 + n*16 + c;
            const int hh  = col / 192;
            const int rem = col - hh * 192;
            const int tt  = rem >> 6;
            const int d   = rem & 63;
            const int bhh = b * HEADS + hh;
            if (tt == 2) {
                const int st_e = q0 >> 6, kk = q0 & 63;
                const int f_e  = (d >> 5) * 4 + (kk >> 4);
                const int ln_e = ((kk >> 3) & 1) * 32 + (d & 31);
                const int e0   = kk & 7;
                ushort4 o;
                o.x = f2bf(acc[m][n][0]); o.y = f2bf(acc[m][n][1]);
                o.z = f2bf(acc[m][n][2]); o.w = f2bf(acc[m][n][3]);
                *(ushort4*)(Vo + (size_t)bhh * (SEQ*HDIM) + st_e*4096 + f_e*512 + ln_e*8 + e0) = o;
            } else if (tt == 1) {
                const int st_e = q0 >> 6;
                const int f_e  = ((q0 >> 5) & 1) * 4 + (d >> 4);
                const int lq_e = q0 & 31;
                const int ln_b = ((d >> 3) & 1) * 32;
                const int e_e  = d & 7;
                unsigned short* dst = Ko + (size_t)bhh * (SEQ*HDIM) + st_e*4096 + f_e*512
                                         + (ln_b + lq_e)*8 + e_e;
#pragma unroll
                for (int j = 0; j < 4; ++j)
                    dst[j*8] = f2bf(acc[m][n][j]);
            } else {
                unsigned short* dst = Qo + ((size_t)bhh * SEQ + q0) * HDIM + d;
#pragma unroll
                for (int j = 0; j < 4; ++j)
                    dst[(size_t)j * HDIM] = f2bf(acc[m][n][j]);
            }
        }
    }
}

// ---------------- causal flash attention, 32x32 swapped, fragment-major K/V ----------------
__global__ __launch_bounds__(512) __attribute__((amdgpu_waves_per_eu(2, 2)))
void k_attention(
    const unsigned short* __restrict__ Qb,
    const unsigned short* __restrict__ Kf,
    const unsigned short* __restrict__ Vf,
    unsigned short* __restrict__ out)
{
    const int t = threadIdx.x, l = t & 63, w = t >> 6;
    const int lq = l & 31, hi = l >> 5;
    const int bid = blockIdx.x;
    const int sbid = (bid & 7) * 32 + (bid >> 3);
    const int bh = sbid >> 3, j = sbid & 7;
    const int qb = (w < 4) ? (4*j + w) : (63 - 4*j - (w - 4));
    const int q  = qb * 32 + lq;

    const unsigned short* Qh  = Qb + (size_t)bh * SEQ * HDIM;
    const unsigned short* Kfh = Kf + (size_t)bh * SEQ * HDIM + l*8;
    const unsigned short* Vfh = Vf + (size_t)bh * SEQ * HDIM + l*8;

    const bf16x8 qf0 = *(const bf16x8*)(Qh + (size_t)q * HDIM      + hi*8);
    const bf16x8 qf1 = *(const bf16x8*)(Qh + (size_t)q * HDIM + 16 + hi*8);
    const bf16x8 qf2 = *(const bf16x8*)(Qh + (size_t)q * HDIM + 32 + hi*8);
    const bf16x8 qf3 = *(const bf16x8*)(Qh + (size_t)q * HDIM + 48 + hi*8);

    f32x16 oT0, oT1;
#pragma unroll
    for (int i = 0; i < 16; ++i) { oT0[i] = 0.f; oT1[i] = 0.f; }
    float lacc0 = 0.f, lacc1 = 0.f, lacc2 = 0.f, lacc3 = 0.f;
    const float kSc = 0.18033688011112042f;   // 0.125 * log2(e)
    const int nst = (qb >> 1) + 1;

    bf16x8 kA0, kA1, kA2, kA3, kA4, kA5, kA6, kA7;
    bf16x8 kB0, kB1, kB2, kB3, kB4, kB5, kB6, kB7;

#define LOADK(stv, KF) do {                                                     \
    const unsigned short* kp_ = Kfh + (size_t)(stv) * 4096;                     \
    KF##0 = *(const bf16x8*)(kp_ +    0); KF##1 = *(const bf16x8*)(kp_ +  512); \
    KF##2 = *(const bf16x8*)(kp_ + 1024); KF##3 = *(const bf16x8*)(kp_ + 1536); \
    KF##4 = *(const bf16x8*)(kp_ + 2048); KF##5 = *(const bf16x8*)(kp_ + 2560); \
    KF##6 = *(const bf16x8*)(kp_ + 3072); KF##7 = *(const bf16x8*)(kp_ + 3584); \
} while (0)

#define STEP(stv, KF) do {                                                      \
    const int kv0_ = (stv) * 64;                                                \
    const unsigned short* vp_ = Vfh + (size_t)(stv) * 4096;                     \
    bf16x8 vf0_ = *(const bf16x8*)(vp_ +    0), vf1_ = *(const bf16x8*)(vp_ +  512); \
    bf16x8 vf2_ = *(const bf16x8*)(vp_ + 1024), vf3_ = *(const bf16x8*)(vp_ + 1536); \
    bf16x8 vf4_ = *(const bf16x8*)(vp_ + 2048), vf5_ = *(const bf16x8*)(vp_ + 2560); \
    bf16x8 vf6_ = *(const bf16x8*)(vp_ + 3072), vf7_ = *(const bf16x8*)(vp_ + 3584); \
    f32x16 sA_, sB_;                                                            \
    _Pragma("unroll")                                                           \
    for (int i = 0; i < 16; ++i) { sA_[i] = 0.f; sB_[i] = 0.f; }               \
    __builtin_amdgcn_s_setprio(1);                                              \
    sA_ = __builtin_amdgcn_mfma_f32_32x32x16_bf16(KF##0, qf0, sA_, 0, 0, 0);    \
    sA_ = __builtin_amdgcn_mfma_f32_32x32x16_bf16(KF##1, qf1, sA_, 0, 0, 0);    \
    sA_ = __builtin_amdgcn_mfma_f32_32x32x16_bf16(KF##2, qf2, sA_, 0, 0, 0);    \
    sA_ = __builtin_amdgcn_mfma_f32_32x32x16_bf16(KF##3, qf3, sA_, 0, 0, 0);    \
    sB_ = __builtin_amdgcn_mfma_f32_32x32x16_bf16(KF##4, qf0, sB_, 0, 0, 0);    \
    sB_ = __builtin_amdgcn_mfma_f32_32x32x16_bf16(KF##5, qf1, sB_, 0, 0, 0);    \
    sB_ = __builtin_amdgcn_mfma_f32_32x32x16_bf16(KF##6, qf2, sB_, 0, 0, 0);    \
    sB_ = __builtin_amdgcn_mfma_f32_32x32x16_bf16(KF##7, qf3, sB_, 0, 0, 0);    \
    __builtin_amdgcn_s_setprio(0);                                              \
    float p_[32];                                                               \
    if ((stv) == nst - 1) {                                                     \
        _Pragma("unroll")                                                       \
        for (int r = 0; r < 16; ++r) {                                          \
            const int key_ = kv0_ + (r & 3) + 8*(r >> 2) + 4*hi;                \
            p_[r]      = (key_      <= q) ? fexp2(sA_[r] * kSc) : 0.f;          \
            p_[16 + r] = (key_ + 32 <= q) ? fexp2(sB_[r] * kSc) : 0.f;          \
        }                                                                       \
    } else {                                                                    \
        _Pragma("unroll")                                                       \
        for (int r = 0; r < 16; ++r) {                                          \
            p_[r]      = fexp2(sA_[r] * kSc);                                   \
            p_[16 + r] = fexp2(sB_[r] * kSc);                                   \
        }                                                                       \
    }                                                                           \
    _Pragma("unroll")                                                           \
    for (int i = 0; i < 32; i += 4) {                                           \
        lacc0 += p_[i]; lacc1 += p_[i+1]; lacc2 += p_[i+2]; lacc3 += p_[i+3];   \
    }                                                                           \
    bf16x8 pa_[4];                                                              \
    _Pragma("unroll")                                                           \
    for (int ks = 0; ks < 4; ++ks) {                                            \
        const int b8_ = ks * 8;                                                 \
        uint32x2 rA_ = __builtin_amdgcn_permlane32_swap(                        \
            cvtpk_bf16(p_[b8_+0], p_[b8_+1]), cvtpk_bf16(p_[b8_+4], p_[b8_+5]), false, false); \
        uint32x2 rB_ = __builtin_amdgcn_permlane32_swap(                        \
            cvtpk_bf16(p_[b8_+2], p_[b8_+3]), cvtpk_bf16(p_[b8_+6], p_[b8_+7]), false, false); \
        union { uint32_t u[4]; bf16x8 v; } pk_;                                 \
        pk_.u[0] = rA_[0]; pk_.u[1] = rB_[0]; pk_.u[2] = rA_[1]; pk_.u[3] = rB_[1]; \
        pa_[ks] = pk_.v;                                                        \
    }                                                                           \
    __builtin_amdgcn_s_setprio(1);                                              \
    oT0 = __builtin_amdgcn_mfma_f32_32x32x16_bf16(vf0_, pa_[0], oT0, 0, 0, 0);  \
    oT0 = __builtin_amdgcn_mfma_f32_32x32x16_bf16(vf1_, pa_[1], oT0, 0, 0, 0);  \
    oT0 = __builtin_amdgcn_mfma_f32_32x32x16_bf16(vf2_, pa_[2], oT0, 0, 0, 0);  \
    oT0 = __builtin_amdgcn_mfma_f32_32x32x16_bf16(vf3_, pa_[3], oT0, 0, 0, 0);  \
    oT1 = __builtin_amdgcn_mfma_f32_32x32x16_bf16(vf4_, pa_[0], oT1, 0, 0, 0);  \
    oT1 = __builtin_amdgcn_mfma_f32_32x32x16_bf16(vf5_, pa_[1], oT1, 0, 0, 0);  \
    oT1 = __builtin_amdgcn_mfma_f32_32x32x16_bf16(vf6_, pa_[2], oT1, 0, 0, 0);  \
    oT1 = __builtin_amdgcn_mfma_f32_32x32x16_bf16(vf7_, pa_[3], oT1, 0, 0, 0);  \
    __builtin_amdgcn_s_setprio(0);                                              \
} while (0)

    LOADK(0, kA);
    int st = 0;
    for (;;) {
        if (st + 1 < nst) LOADK(st + 1, kB);
        STEP(st, kA);
        if (++st >= nst) break;
        if (st + 1 < nst) LOADK(st + 1, kA);
        STEP(st, kB);
        if (++st >= nst) break;
    }
#undef LOADK
#undef STEP

    float lsum = (lacc0 + lacc1) + (lacc2 + lacc3);
    lsum += __shfl_xor(lsum, 32, 64);
    const float inv = 1.f / lsum;
    unsigned short* ob = out + ((size_t)bh * SEQ + q) * HDIM;
#pragma unroll
    for (int m2 = 0; m2 < 4; ++m2) {
        ushort4 o0, o1;
        o0.x = f2bf(oT0[m2*4+0] * inv); o0.y = f2bf(oT0[m2*4+1] * inv);
        o0.z = f2bf(oT0[m2*4+2] * inv); o0.w = f2bf(oT0[m2*4+3] * inv);
        o1.x = f2bf(oT1[m2*4+0] * inv); o1.y = f2bf(oT1[m2*4+1] * inv);
        o1.z = f2bf(oT1[m2*4+2] * inv); o1.w = f2bf(oT1[m2*4+3] * inv);
        *(ushort4*)(ob +      m2*8 + hi*4) = o0;
        *(ushort4*)(ob + 32 + m2*8 + hi*4) = o1;
    }
}

// ---------------- host launcher ----------------
extern "C" void kernel_launch(void* const* d_in, const int* in_sizes, int n_in,
                              void* d_out, int out_size, void* d_ws, size_t ws_size,
                              hipStream_t stream)
{
    (void)in_sizes; (void)n_in; (void)out_size; (void)ws_size;
    const float* x      = (const float*)d_in[0];
    const float* w_qkv  = (const float*)d_in[1];
    const float* w_proj = (const float*)d_in[2];
    const float* b_proj = (const float*)d_in[3];
    const float* w1     = (const float*)d_in[4];
    const float* b1     = (const float*)d_in[5];
    const float* w2     = (const float*)d_in[6];
    const float* b2     = (const float*)d_in[7];
    const float* g1     = (const float*)d_in[8];
    const float* be1    = (const float*)d_in[9];
    const float* g2     = (const float*)d_in[10];
    const float* be2    = (const float*)d_in[11];

    char* ws = (char*)d_ws;
    size_t o = 0;
    auto take = [&](size_t bytes) -> char* {
        char* p = ws + o;
        o += (bytes + 255) & ~(size_t)255;
        return p;
    };
    unsigned short* wqkvT  = (unsigned short*)take(3072ull * 1024 * 2);
    unsigned short* wprojT = (unsigned short*)take(1024ull * 1024 * 2);
    unsigned short* w1T    = (unsigned short*)take(4096ull * 1024 * 2);
    unsigned short* w2T    = (unsigned short*)take(1024ull * 4096 * 2);
    unsigned short* h      = (unsigned short*)take(4096ull * 1024 * 2);   // LN out (reused)
    unsigned short* Qb     = (unsigned short*)take(4096ull * 1024 * 2);
    unsigned short* Kfb    = (unsigned short*)take(4096ull * 1024 * 2);
    unsigned short* Vfb    = (unsigned short*)take(4096ull * 1024 * 2);
    unsigned short* attno  = (unsigned short*)take(4096ull * 1024 * 2);
    float*          x2     = (float*)take(4096ull * 1024 * 4);
    unsigned short* f1     = Qb;   // alias: Q/Kf/Vf/attno (32MB) dead before FF1 writes

    // prep: all four weight transposes + LN1 in ONE launch
    k_prep<<<16384, 256, 0, stream>>>(
        w_qkv, w_proj, w1, w2, wqkvT, wprojT, w1T, w2T, x, g1, be1, h);

    // QKV GEMM (256x192 tiles, 256 wgs = full CU fill) -> Q / Kf / Vf
    k_gemm_qkv<<<dim3(16, 16), 512, 0, stream>>>(h, wqkvT, Qb, Kfb, Vfb, 1024);
    // attention: 256 blocks x 512 threads (8 waves, balanced qb pairing)
    k_attention<<<256, 512, 0, stream>>>(Qb, Kfb, Vfb, attno);
    // proj + bias + residual(x) -> x2 (fp32)  [128^2 v10: N=1024, K=1024]
    k_gemm_bt<5, float><<<dim3(8, 32), 512, 0, stream>>>(
        attno, wprojT, b_proj, x, x2, ROWS, 1024, 1024);
    // LN2
    k_layernorm<<<4096, 256, 0, stream>>>(x2, g2, be2, h);
    // FF1 + bias + relu -> bf16 (256^2 v7, BK=32 single-barrier) [R9/R10-verified]
    k_gemm256<3, unsigned short><<<dim3(16, 16), 512, 0, stream>>>(
        h, w1T, b1, f1, ROWS, 4096, 1024);
    // FF2 + bias + residual(x2) -> d_out (fp32)  [128^2 v10: N=1024, K=4096]
    k_gemm_bt<5, float><<<dim3(8, 32), 512, 0, stream>>>(
        f1, w2T, b2, x2, (float*)d_out, ROWS, 1024, 4096);
}